// Round 5
// baseline (631.655 us; speedup 1.0000x reference)
//
#include <hip/hip_runtime.h>
#include <cstdint>
#include <cstddef>

// Problem constants: B=4, S=2048, D=1024
#define BB 4
#define SS 2048
#define DD 1024

typedef _Float16 f16;
typedef _Float16 f16x8 __attribute__((ext_vector_type(8)));
typedef _Float16 f16x4 __attribute__((ext_vector_type(4)));
typedef float fx4 __attribute__((ext_vector_type(4)));

enum { EPI_BIAS = 0, EPI_MASKEXP = 1, EPI_ROWSCALE = 2, EPI_QKV = 3 };

// ---------------------------------------------------------------------------
// Barrier-free NT GEMM: C[M,N] = epilogue(scale * (A[M,K] @ Bt[N,K]^T))
// 128x128 block tile, 4 waves (2x2), each wave 64x64, mfma_f32_16x16x32_f16.
//
// R5: NO LDS, NO barriers in the K-loop. In NT layout the MFMA A and B
// fragments are both "16 rows x 16B k-chunk" — loadable directly to VGPRs
// with global_load_dwordx4. Register double-buffer: load iter i+1's 8
// fragments, then run iter i's 16 MFMAs. K_ITERS is a template constant ->
// full unroll, k-offsets become 13-bit immediates, and the compiler emits
// fine-grained s_waitcnt vmcnt(N) — loads stay in flight across iters
// (the AITER pattern). R4 showed the global_load_lds + __syncthreads
// structure stalls ~65% of cycles on the vmcnt(0) barrier drain regardless
// of double-buffering. Cross-wave reuse now comes from per-CU L1 instead
// of LDS (2x L1 traffic; L1 ceiling still ~2x above demand at target util).
//
// EPI_QKV (GEMM1): tileN<2048 -> bias write to packed QK[8192x2048];
//   tileN>=2048 -> V^T written straight to Vt[b][d][s] (lane holds 4
//   consecutive s -> aligned f16x4 stores).
// EPI_MASKEXP: C = mask ? 0 : exp(scale*acc); atomic row sums. Mask tile
//   staged to a 16KB LDS buffer as u8 (coalesced int4 loads, quad-swizzled).
//   (No max-subtraction: scores ~N(0,1); f16 overflow needs >11 sigma;
//    masked -> exact 0.)
// EPI_ROWSCALE: C = acc * scale / rowSum[row]   (softmax normalization)
// ---------------------------------------------------------------------------
template <typename OutT, int MODE, int K_ITERS>
__global__ __launch_bounds__(256) void gemm_nt(
    const f16* __restrict__ A, long long strideA, int lda,
    const f16* __restrict__ Bt, long long strideB, int ldb,
    OutT* __restrict__ C, long long strideC, int ldc,
    const float* __restrict__ bias, const int* __restrict__ mask,
    float* __restrict__ rowSum, f16* __restrict__ vt, float scale) {
  const int t = threadIdx.x;
  const int lane = t & 63;
  const int wid = t >> 6;
  const long long bz = blockIdx.z;
  const int tileM = blockIdx.y * 128;
  const int tileN = blockIdx.x * 128;

  const f16* Ab = A + bz * strideA;
  const f16* Bb = Bt + bz * strideB;
  OutT* Cb = C + bz * strideC;

  const int waveM = (wid >> 1) * 64;
  const int waveN = (wid & 1) * 64;
  const int r16 = lane & 15;
  const int quad = lane >> 4;

  // Fragment base pointers: row = (tile + wave + x*16 + r16), k-chunk = quad*8.
  const f16* pA[4];
  const f16* pB[4];
#pragma unroll
  for (int x = 0; x < 4; ++x) {
    pA[x] = Ab + (size_t)(tileM + waveM + x * 16 + r16) * lda + quad * 8;
    pB[x] = Bb + (size_t)(tileN + waveN + x * 16 + r16) * ldb + quad * 8;
  }

  fx4 acc[4][4] = {};

  f16x8 a0[4], b0[4];
#pragma unroll
  for (int x = 0; x < 4; ++x) {
    a0[x] = *(const f16x8*)(pA[x]);
    b0[x] = *(const f16x8*)(pB[x]);
  }

#pragma unroll
  for (int i = 0; i < K_ITERS; ++i) {
    f16x8 a1[4], b1[4];
    if (i + 1 < K_ITERS) {
      const int k = (i + 1) * 32;
#pragma unroll
      for (int x = 0; x < 4; ++x) {
        a1[x] = *(const f16x8*)(pA[x] + k);
        b1[x] = *(const f16x8*)(pB[x] + k);
      }
    }
#pragma unroll
    for (int x = 0; x < 4; ++x)
#pragma unroll
      for (int j = 0; j < 4; ++j)
        acc[x][j] =
            __builtin_amdgcn_mfma_f32_16x16x32_f16(a0[x], b0[j], acc[x][j], 0, 0, 0);
#pragma unroll
    for (int x = 0; x < 4; ++x) {
      a0[x] = a1[x];
      b0[x] = b1[x];
    }
  }

  // C/D layout (verified, dtype-independent): col = lane&15, row = quad*4 + reg.
  if constexpr (MODE == EPI_BIAS) {
#pragma unroll
    for (int j = 0; j < 4; ++j) {
      const int col = tileN + waveN + j * 16 + r16;
      const float bv = bias[col];
#pragma unroll
      for (int i = 0; i < 4; ++i) {
#pragma unroll
        for (int r = 0; r < 4; ++r) {
          const int row = tileM + waveM + i * 16 + quad * 4 + r;
          Cb[(size_t)row * ldc + col] = (OutT)(acc[i][j][r] * scale + bv);
        }
      }
    }
  } else if constexpr (MODE == EPI_QKV) {
    if (tileN < 2 * DD) {
      // packed QK output [8192 x 2048]
#pragma unroll
      for (int j = 0; j < 4; ++j) {
        const int col = tileN + waveN + j * 16 + r16;
        const float bv = bias[col];
#pragma unroll
        for (int i = 0; i < 4; ++i) {
#pragma unroll
          for (int r = 0; r < 4; ++r) {
            const int row = tileM + waveM + i * 16 + quad * 4 + r;
            Cb[(size_t)row * ldc + col] = (OutT)(acc[i][j][r] + bv);
          }
        }
      }
    } else {
      // V columns -> write transposed into Vt[b][d][s]
      const int b = tileM >> 11;  // 128-row tiles never straddle batch
      const int s0 = (tileM & 2047) + waveM;
      f16* vb = vt + (size_t)b * DD * SS;
#pragma unroll
      for (int j = 0; j < 4; ++j) {
        const int col = tileN + waveN + j * 16 + r16;
        const float bv = bias[col];
        const int d = col - 2 * DD;
#pragma unroll
        for (int i = 0; i < 4; ++i) {
          const int s = s0 + i * 16 + quad * 4;
          f16x4 v4;
#pragma unroll
          for (int r = 0; r < 4; ++r) v4[r] = (f16)(acc[i][j][r] + bv);
          *(f16x4*)&vb[(size_t)d * SS + s] = v4;
        }
      }
    }
  } else if constexpr (MODE == EPI_MASKEXP) {
    // --- stage 128x128 mask tile into LDS as u8 (coalesced int4) ---
    __shared__ uint8_t lm[16384];
    const int* maskb = mask + bz * (long long)SS * SS;
#pragma unroll
    for (int it = 0; it < 16; ++it) {
      const int f = it * 256 + t;  // int4 index within tile: 4096 total
      const int r = f >> 5;        // tile row (32 int4 per row)
      const int q = f & 31;
      const int4 mv =
          *(const int4*)&maskb[(size_t)(tileM + r) * SS + tileN + q * 4];
      uchar4 mb;
      mb.x = mv.x ? 1 : 0;
      mb.y = mv.y ? 1 : 0;
      mb.z = mv.z ? 1 : 0;
      mb.w = mv.w ? 1 : 0;
      const int c4 = (q * 4) ^ (((r >> 2) & 3) * 32);  // bank swizzle
      *(uchar4*)&lm[r * 128 + c4] = mb;
    }
    __syncthreads();

#pragma unroll
    for (int i = 0; i < 4; ++i) {
#pragma unroll
      for (int r = 0; r < 4; ++r) {
        const int lr = waveM + i * 16 + quad * 4 + r;
        const int row = tileM + lr;
        const int swm = ((lr >> 2) & 3) * 32;
        float part = 0.0f;
#pragma unroll
        for (int j = 0; j < 4; ++j) {
          const int lc = waveN + j * 16 + r16;
          const int mv = lm[lr * 128 + (lc ^ swm)];
          const float e = mv ? 0.0f : __expf(acc[i][j][r] * scale);
          Cb[(size_t)row * ldc + tileN + lc] = (OutT)e;
          part += e;
        }
#pragma unroll
        for (int d = 1; d < 16; d <<= 1) part += __shfl_xor(part, d, 64);
        if (r16 == 0) atomicAdd(&rowSum[bz * SS + row], part);
      }
    }
  } else {  // EPI_ROWSCALE
#pragma unroll
    for (int i = 0; i < 4; ++i) {
#pragma unroll
      for (int r = 0; r < 4; ++r) {
        const int row = tileM + waveM + i * 16 + quad * 4 + r;
        const float inv = scale / rowSum[bz * SS + row];
#pragma unroll
        for (int j = 0; j < 4; ++j) {
          const int col = tileN + waveN + j * 16 + r16;
          Cb[(size_t)row * ldc + col] = (OutT)(acc[i][j][r] * inv);
        }
      }
    }
  }
}

// ---------------------------------------------------------------------------
// fp32 -> f16 elementwise convert (x4 vectorized)
// ---------------------------------------------------------------------------
__global__ __launch_bounds__(256) void k_conv(const float* __restrict__ in,
                                              f16* __restrict__ out, int n4) {
  const int i = blockIdx.x * 256 + threadIdx.x;
  if (i >= n4) return;
  const float4 v = ((const float4*)in)[i];
  f16x4 h = {(f16)v.x, (f16)v.y, (f16)v.z, (f16)v.w};
  ((f16x4*)out)[i] = h;
}

__global__ __launch_bounds__(256) void k_zero(float* __restrict__ p, int n) {
  const int i = blockIdx.x * 256 + threadIdx.x;
  if (i < n) p[i] = 0.0f;
}

// ---------------------------------------------------------------------------
// fp32 [R][C] -> f16 [C][R] tiled transpose-convert. grid (C/32, R/32), block (32,8)
// ---------------------------------------------------------------------------
__global__ __launch_bounds__(256) void k_transpose_conv(const float* __restrict__ in,
                                                        f16* __restrict__ out, int R,
                                                        int C) {
  __shared__ float tile[32][33];
  const int bx = blockIdx.x * 32;
  const int by = blockIdx.y * 32;
  const int tx = threadIdx.x;
  const int ty = threadIdx.y;
  for (int i = ty; i < 32; i += 8)
    tile[i][tx] = in[(size_t)(by + i) * C + bx + tx];
  __syncthreads();
  for (int i = ty; i < 32; i += 8)
    out[(size_t)(bx + i) * R + by + tx] = (f16)tile[tx][i];
}

// ---------------------------------------------------------------------------
// kernel_launch
// inputs: X[4,2048,1024]f32, mask[4,2048,2048]i32, W_qkv[1024,3072]f32,
//         b_qkv[3072]f32, W_out[1024,1024]f32, b_out[1024]f32
// out:    [4,2048,1024] f32
// ---------------------------------------------------------------------------
extern "C" void kernel_launch(void* const* d_in, const int* in_sizes, int n_in,
                              void* d_out, int out_size, void* d_ws, size_t ws_size,
                              hipStream_t stream) {
  const float* X = (const float*)d_in[0];
  const int* mask = (const int*)d_in[1];
  const float* Wqkv = (const float*)d_in[2];
  const float* bqkv = (const float*)d_in[3];
  const float* Wout = (const float*)d_in[4];
  const float* bout = (const float*)d_in[5];
  float* out = (float*)d_out;

  char* ws = (char*)d_ws;
  // ws layout (bytes); total ~125.9 MB
  f16* Xh = (f16*)(ws + 0);                    // 8192*1024   (16.78 MB)
  f16* Wqkvt = (f16*)(ws + 16777216);          // 3072*1024   ( 6.29 MB)
  f16* Woutt = (f16*)(ws + 23068672);          // 1024*1024   ( 2.10 MB)
  f16* QK = (f16*)(ws + 25165824);             // 8192*2048   (33.55 MB) packed Q|K
  f16* Vt = (f16*)(ws + 58720256);             // 4*1024*2048 (16.78 MB)
  f16* E = (f16*)(ws + 75497472);              // 4*2048*2048 (33.55 MB) exp(scores)
  f16* Ctx = (f16*)(ws + 109051904);           // 8192*1024   (16.78 MB)
  float* rowSum = (float*)(ws + 125829120);    // 8192 f32    (32 KB)

  // 1) X -> f16
  k_conv<<<dim3(8192), dim3(256), 0, stream>>>(X, Xh, 8388608 / 4);
  // 2) W_qkv^T, W_out^T (f16); zero softmax row sums
  k_transpose_conv<<<dim3(96, 32), dim3(32, 8), 0, stream>>>(Wqkv, Wqkvt, DD, 3 * DD);
  k_transpose_conv<<<dim3(32, 32), dim3(32, 8), 0, stream>>>(Wout, Woutt, DD, DD);
  k_zero<<<dim3(32), dim3(256), 0, stream>>>(rowSum, BB * SS);

  // 3) QKV proj [8192 x 3072], K=1024: Q,K -> packed QK; V -> Vt (transposed)
  gemm_nt<f16, EPI_QKV, 32><<<dim3(24, 64, 1), dim3(256), 0, stream>>>(
      Xh, 0LL, DD, Wqkvt, 0LL, DD, QK, 0LL, 2 * DD, bqkv, nullptr, nullptr, Vt,
      1.0f);

  // 4) E = where(mask, 0, exp(Q @ K^T / 32)); rowSum += row sums  [2048 x 2048] x4
  gemm_nt<f16, EPI_MASKEXP, 32><<<dim3(16, 16, 4), dim3(256), 0, stream>>>(
      QK, (long long)SS * 2 * DD, 2 * DD, QK + DD, (long long)SS * 2 * DD, 2 * DD,
      E, (long long)SS * SS, SS, nullptr, mask, rowSum, nullptr, 0.03125f);

  // 5) ctx = (E @ V) / rowSum   [2048 x 1024] x4, K=2048
  gemm_nt<f16, EPI_ROWSCALE, 64><<<dim3(8, 16, 4), dim3(256), 0, stream>>>(
      E, (long long)SS * SS, SS, Vt, (long long)DD * SS, SS, Ctx,
      (long long)SS * DD, DD, nullptr, nullptr, rowSum, nullptr, 1.0f);

  // 6) out = ctx @ W_out + b   [8192 x 1024], K=1024, fp32 out
  gemm_nt<float, EPI_BIAS, 32><<<dim3(8, 64, 1), dim3(256), 0, stream>>>(
      Ctx, 0LL, DD, Woutt, 0LL, DD, out, 0LL, DD, bout, nullptr, nullptr, nullptr,
      1.0f);
}

// Round 7
// 336.671 us; speedup vs baseline: 1.8762x; 1.8762x over previous
//
#include <hip/hip_runtime.h>
#include <cstdint>
#include <cstddef>

// Problem constants: B=4, S=2048, D=1024
#define BB 4
#define SS 2048
#define DD 1024

typedef _Float16 f16;
typedef _Float16 f16x8 __attribute__((ext_vector_type(8)));
typedef _Float16 f16x4 __attribute__((ext_vector_type(4)));
typedef float fx4 __attribute__((ext_vector_type(4)));

// ---------------------------------------------------------------------------
// async global->LDS, 16B per lane. LDS dest must be wave-uniform base + lane*16.
// ---------------------------------------------------------------------------
__device__ __forceinline__ void async_copy16(void* lds, const void* g) {
  __builtin_amdgcn_global_load_lds(
      (__attribute__((address_space(1))) void*)const_cast<void*>(g),
      (__attribute__((address_space(3))) void*)lds,
      16, 0, 0);
}

enum { EPI_BIAS = 0, EPI_MASKEXP = 1, EPI_ROWSCALE = 2, EPI_QKV = 3 };

// ---------------------------------------------------------------------------
// NT GEMM: C[M,N] = epilogue(scale * (A[M,K] @ Bt[N,K]^T))
// 128x128 tile, BK=32, 256 threads (4 waves 2x2), mfma_f32_16x16x32_f16.
// R4 structure (proven 356us): LDS double-buffer, one barrier/iter.
//
// R7 HAZARD RULE (from R6's nondeterministic failure): regular VGPR global
// loads must NEVER be in flight together with global_load_lds LDS-DMA (both
// share vmcnt; mixed retirement under-waits). So the MASKEXP mask pack runs
// FIRST, then __syncthreads() (drains pack vmcnt, publishes lmb, and fences
// compiler scheduling), and only then is any LDS-DMA issued. Epilogue loads
// are likewise DMA-free (last prefetch drained at the final barrier) — the
// invariant every passing round (R1-R4) satisfied.
//
// LDS K-chunks XOR-swizzled (R2: 6.29e6 conflict cycles -> 0). Staging
// thread t writes LDS chunk t; fetches global k-chunk (t&3)^((t>>3)&3).
// Read side: frag(row,quad) at chunk row*4 + (quad ^ ((r16>>1)&3)).
//
// EPI_QKV (GEMM1): tileN<2048 -> bias write to packed QK[8192x2048];
//   tileN>=2048 -> V^T written straight to Vt[b][d][s].
// EPI_MASKEXP: C = mask ? 0 : exp(scale*acc); atomic row sums. Mask tile
//   packed pre-loop into a 2KB LDS bitmask (verified fwd+inverse mapping);
//   epilogue mask read = broadcast ds_read_b32 + bit test. 34.8KB LDS keeps
//   4 blocks/CU (vs 48KB u8 tile -> 3).
//   (No max-subtraction: scores ~N(0,1); f16 overflow needs >11 sigma;
//    masked -> exact 0.)
// EPI_ROWSCALE: C = acc * scale / rowSum[row]   (softmax normalization)
// ---------------------------------------------------------------------------
template <typename OutT, int MODE>
__global__ __launch_bounds__(256, 2) void gemm_nt(
    const f16* __restrict__ A, long long strideA, int lda,
    const f16* __restrict__ Bt, long long strideB, int ldb,
    OutT* __restrict__ C, long long strideC, int ldc,
    const float* __restrict__ bias, const int* __restrict__ mask,
    float* __restrict__ rowSum, f16* __restrict__ vt, float scale, int K) {
  // 32KB dbuf (2 x (As 8K + Bs 8K)); +2KB mask bitmask for MASKEXP only
  constexpr int SMEM_BYTES = (MODE == EPI_MASKEXP) ? 34816 : 32768;
  __shared__ __align__(16) char smem[SMEM_BYTES];
  uint32_t* lmb = (uint32_t*)(smem + 32768);  // 512 words = 128x128 bits

  const int t = threadIdx.x;
  const int lane = t & 63;
  const int wid = t >> 6;
  const long long bz = blockIdx.z;
  const int tileM = blockIdx.y * 128;
  const int tileN = blockIdx.x * 128;

  const f16* Ab = A + bz * strideA;
  const f16* Bb = Bt + bz * strideB;
  OutT* Cb = C + bz * strideC;

  // Staging map (swizzled): row = t/4, global k-chunk = (t&3)^((t>>3)&3).
  const int sr = t >> 2;
  const int sc = (((t & 3) ^ ((t >> 3) & 3)) * 8);
  const f16* pa0 = Ab + (size_t)(tileM + sr) * lda + sc;
  const f16* pa1 = Ab + (size_t)(tileM + 64 + sr) * lda + sc;
  const f16* pb0 = Bb + (size_t)(tileN + sr) * ldb + sc;
  const f16* pb1 = Bb + (size_t)(tileN + 64 + sr) * ldb + sc;
  const int tb = t * 16;  // byte offset of this thread's 16B chunk

  const int waveM = (wid >> 1) * 64;
  const int waveN = (wid & 1) * 64;
  const int r16 = lane & 15;
  const int quad = lane >> 4;
  const int sw = (r16 >> 1) & 3;  // read-side swizzle term

  if constexpr (MODE == EPI_MASKEXP) {
    // Pack 128x128 int32 mask tile -> 512-word LDS bitmask. Runs BEFORE any
    // LDS-DMA is issued (hazard rule above). Thread t, step it: int4 cell
    // f = it*256+t covers row f>>5, cols (f&31)*4..+3 -> word 32it+(t>>3),
    // bits 4(t&7)..+3; 8-lane shfl-OR butterfly assembles each word.
    const int* maskb = mask + bz * (long long)SS * SS;
#pragma unroll
    for (int it = 0; it < 16; ++it) {
      const int f = it * 256 + t;
      const int4 mv =
          *(const int4*)&maskb[(size_t)(tileM + (f >> 5)) * SS + tileN + (f & 31) * 4];
      uint32_t val = (mv.x ? 1u : 0u) | (mv.y ? 2u : 0u) | (mv.z ? 4u : 0u) |
                     (mv.w ? 8u : 0u);
      val <<= (t & 7) * 4;
      val |= __shfl_xor(val, 1, 64);
      val |= __shfl_xor(val, 2, 64);
      val |= __shfl_xor(val, 4, 64);
      if ((t & 7) == 0) lmb[it * 32 + (t >> 3)] = val;
    }
    __syncthreads();  // drain pack vmcnt + publish lmb BEFORE first LDS-DMA
  }

  const int nIter = K >> 5;
  // prologue: prefetch tile 0 into buffer 0
  {
    char* b0 = smem;
    async_copy16(b0 + tb, pa0);
    async_copy16(b0 + 4096 + tb, pa1);
    async_copy16(b0 + 8192 + tb, pb0);
    async_copy16(b0 + 12288 + tb, pb1);
  }

  fx4 acc[4][4] = {};

#pragma unroll 2
  for (int i = 0; i < nIter; ++i) {
    __syncthreads();  // drains vmcnt (prefetch i) + lgkm (reads of i-1)
    if (i + 1 < nIter) {
      char* nb = smem + ((i + 1) & 1) * 16384;
      const int k = (i + 1) << 5;
      async_copy16(nb + tb, pa0 + k);
      async_copy16(nb + 4096 + tb, pa1 + k);
      async_copy16(nb + 8192 + tb, pb0 + k);
      async_copy16(nb + 12288 + tb, pb1 + k);
    }
    const f16* As = (const f16*)(smem + (i & 1) * 16384);
    const f16* Bs = As + 4096;

    f16x8 af[4], bf[4];
#pragma unroll
    for (int x = 0; x < 4; ++x)
      af[x] = *(const f16x8*)&As[(waveM + x * 16 + r16) * 32 + (quad ^ sw) * 8];
#pragma unroll
    for (int x = 0; x < 4; ++x)
      bf[x] = *(const f16x8*)&Bs[(waveN + x * 16 + r16) * 32 + (quad ^ sw) * 8];

#pragma unroll
    for (int x = 0; x < 4; ++x)
#pragma unroll
      for (int j = 0; j < 4; ++j)
        acc[x][j] =
            __builtin_amdgcn_mfma_f32_16x16x32_f16(af[x], bf[j], acc[x][j], 0, 0, 0);
  }

  // C/D layout (verified, dtype-independent): col = lane&15, row = quad*4 + reg.
  if constexpr (MODE == EPI_BIAS) {
#pragma unroll
    for (int j = 0; j < 4; ++j) {
      const int col = tileN + waveN + j * 16 + r16;
      const float bv = bias[col];
#pragma unroll
      for (int i = 0; i < 4; ++i) {
#pragma unroll
        for (int r = 0; r < 4; ++r) {
          const int row = tileM + waveM + i * 16 + quad * 4 + r;
          Cb[(size_t)row * ldc + col] = (OutT)(acc[i][j][r] * scale + bv);
        }
      }
    }
  } else if constexpr (MODE == EPI_QKV) {
    if (tileN < 2 * DD) {
      // packed QK output [8192 x 2048]
#pragma unroll
      for (int j = 0; j < 4; ++j) {
        const int col = tileN + waveN + j * 16 + r16;
        const float bv = bias[col];
#pragma unroll
        for (int i = 0; i < 4; ++i) {
#pragma unroll
          for (int r = 0; r < 4; ++r) {
            const int row = tileM + waveM + i * 16 + quad * 4 + r;
            Cb[(size_t)row * ldc + col] = (OutT)(acc[i][j][r] + bv);
          }
        }
      }
    } else {
      // V columns -> write transposed into Vt[b][d][s]
      const int b = tileM >> 11;  // 128-row tiles never straddle batch
      const int s0 = (tileM & 2047) + waveM;
      f16* vb = vt + (size_t)b * DD * SS;
#pragma unroll
      for (int j = 0; j < 4; ++j) {
        const int col = tileN + waveN + j * 16 + r16;
        const float bv = bias[col];
        const int d = col - 2 * DD;
#pragma unroll
        for (int i = 0; i < 4; ++i) {
          const int s = s0 + i * 16 + quad * 4;
          f16x4 v4;
#pragma unroll
          for (int r = 0; r < 4; ++r) v4[r] = (f16)(acc[i][j][r] + bv);
          *(f16x4*)&vb[(size_t)d * SS + s] = v4;
        }
      }
    }
  } else if constexpr (MODE == EPI_MASKEXP) {
    // Bitmask read: word(lr,lc) = lr*4 + (lc>>5), bit lc&31. Address is
    // r16-uniform (broadcast), 4 words across quads — conflict-free.
#pragma unroll
    for (int i = 0; i < 4; ++i) {
#pragma unroll
      for (int r = 0; r < 4; ++r) {
        const int lr = waveM + i * 16 + quad * 4 + r;
        const int row = tileM + lr;
        const uint32_t w0 = lmb[lr * 4 + (waveN >> 5)];
        const uint32_t w1 = lmb[lr * 4 + (waveN >> 5) + 1];
        float part = 0.0f;
#pragma unroll
        for (int j = 0; j < 4; ++j) {
          const int lc = waveN + j * 16 + r16;
          const int bitpos = j * 16 + r16;  // within w0:w1
          const uint32_t mv = ((j < 2 ? w0 : w1) >> (bitpos & 31)) & 1u;
          const float e = mv ? 0.0f : __expf(acc[i][j][r] * scale);
          Cb[(size_t)row * ldc + tileN + lc] = (OutT)e;
          part += e;
        }
#pragma unroll
        for (int d = 1; d < 16; d <<= 1) part += __shfl_xor(part, d, 64);
        if (r16 == 0) atomicAdd(&rowSum[bz * SS + row], part);
      }
    }
  } else {  // EPI_ROWSCALE
#pragma unroll
    for (int i = 0; i < 4; ++i) {
#pragma unroll
      for (int r = 0; r < 4; ++r) {
        const int row = tileM + waveM + i * 16 + quad * 4 + r;
        const float inv = scale / rowSum[bz * SS + row];
#pragma unroll
        for (int j = 0; j < 4; ++j) {
          const int col = tileN + waveN + j * 16 + r16;
          Cb[(size_t)row * ldc + col] = (OutT)(acc[i][j][r] * inv);
        }
      }
    }
  }
}

// ---------------------------------------------------------------------------
// Merged prep: X->f16 conv | W_qkv^T | W_out^T | rowSum zero, one dispatch.
// Block-uniform path select. grid = 8192 + 3072 + 1024 + 32 = 12320 x 256.
// ---------------------------------------------------------------------------
__global__ __launch_bounds__(256) void k_prep(
    const float* __restrict__ X, f16* __restrict__ Xh,
    const float* __restrict__ Wqkv, f16* __restrict__ Wqkvt,
    const float* __restrict__ Wout, f16* __restrict__ Woutt,
    float* __restrict__ rowSum) {
  int bid = blockIdx.x;
  const int t = threadIdx.x;
  if (bid < 8192) {  // X conv: 2097152 float4s
    const int i = bid * 256 + t;
    const float4 v = ((const float4*)X)[i];
    f16x4 h = {(f16)v.x, (f16)v.y, (f16)v.z, (f16)v.w};
    ((f16x4*)Xh)[i] = h;
    return;
  }
  bid -= 8192;
  __shared__ float tile[32][33];
  const int tx = t & 31, ty = t >> 5;
  if (bid < 3072) {  // Wqkv [1024][3072] -> Wqkvt [3072][1024]
    const int bx = (bid % 96) * 32, by = (bid / 96) * 32;
    for (int i2 = ty; i2 < 32; i2 += 8)
      tile[i2][tx] = Wqkv[(size_t)(by + i2) * 3072 + bx + tx];
    __syncthreads();
    for (int i2 = ty; i2 < 32; i2 += 8)
      Wqkvt[(size_t)(bx + i2) * 1024 + by + tx] = (f16)tile[tx][i2];
    return;
  }
  bid -= 3072;
  if (bid < 1024) {  // Wout [1024][1024] -> Woutt [1024][1024]
    const int bx = (bid & 31) * 32, by = (bid >> 5) * 32;
    for (int i2 = ty; i2 < 32; i2 += 8)
      tile[i2][tx] = Wout[(size_t)(by + i2) * 1024 + bx + tx];
    __syncthreads();
    for (int i2 = ty; i2 < 32; i2 += 8)
      Woutt[(size_t)(bx + i2) * 1024 + by + tx] = (f16)tile[tx][i2];
    return;
  }
  bid -= 1024;  // rowSum zero: 32 blocks x 256 = 8192
  rowSum[bid * 256 + t] = 0.0f;
}

// ---------------------------------------------------------------------------
// kernel_launch
// inputs: X[4,2048,1024]f32, mask[4,2048,2048]i32, W_qkv[1024,3072]f32,
//         b_qkv[3072]f32, W_out[1024,1024]f32, b_out[1024]f32
// out:    [4,2048,1024] f32
// ---------------------------------------------------------------------------
extern "C" void kernel_launch(void* const* d_in, const int* in_sizes, int n_in,
                              void* d_out, int out_size, void* d_ws, size_t ws_size,
                              hipStream_t stream) {
  const float* X = (const float*)d_in[0];
  const int* mask = (const int*)d_in[1];
  const float* Wqkv = (const float*)d_in[2];
  const float* bqkv = (const float*)d_in[3];
  const float* Wout = (const float*)d_in[4];
  const float* bout = (const float*)d_in[5];
  float* out = (float*)d_out;

  char* ws = (char*)d_ws;
  // ws layout (bytes); total ~125.9 MB
  f16* Xh = (f16*)(ws + 0);                    // 8192*1024   (16.78 MB)
  f16* Wqkvt = (f16*)(ws + 16777216);          // 3072*1024   ( 6.29 MB)
  f16* Woutt = (f16*)(ws + 23068672);          // 1024*1024   ( 2.10 MB)
  f16* QK = (f16*)(ws + 25165824);             // 8192*2048   (33.55 MB) packed Q|K
  f16* Vt = (f16*)(ws + 58720256);             // 4*1024*2048 (16.78 MB)
  f16* E = (f16*)(ws + 75497472);              // 4*2048*2048 (33.55 MB) exp(scores)
  f16* Ctx = (f16*)(ws + 109051904);           // 8192*1024   (16.78 MB)
  float* rowSum = (float*)(ws + 125829120);    // 8192 f32    (32 KB)

  // 1) merged prep: conv + both W transposes + rowSum zero
  k_prep<<<dim3(12320), dim3(256), 0, stream>>>(X, Xh, Wqkv, Wqkvt, Wout, Woutt,
                                                rowSum);

  // 2) QKV proj [8192 x 3072], K=1024: Q,K -> packed QK; V -> Vt (transposed)
  gemm_nt<f16, EPI_QKV><<<dim3(24, 64, 1), dim3(256), 0, stream>>>(
      Xh, 0LL, DD, Wqkvt, 0LL, DD, QK, 0LL, 2 * DD, bqkv, nullptr, nullptr, Vt,
      1.0f, DD);

  // 3) E = where(mask, 0, exp(Q @ K^T / 32)); rowSum += row sums  [2048 x 2048] x4
  gemm_nt<f16, EPI_MASKEXP><<<dim3(16, 16, 4), dim3(256), 0, stream>>>(
      QK, (long long)SS * 2 * DD, 2 * DD, QK + DD, (long long)SS * 2 * DD, 2 * DD,
      E, (long long)SS * SS, SS, nullptr, mask, rowSum, nullptr, 0.03125f, DD);

  // 4) ctx = (E @ V) / rowSum   [2048 x 1024] x4, K=2048
  gemm_nt<f16, EPI_ROWSCALE><<<dim3(8, 16, 4), dim3(256), 0, stream>>>(
      E, (long long)SS * SS, SS, Vt, (long long)DD * SS, SS, Ctx,
      (long long)SS * DD, DD, nullptr, nullptr, rowSum, nullptr, 1.0f, SS);

  // 5) out = ctx @ W_out + b   [8192 x 1024], K=1024, fp32 out
  gemm_nt<float, EPI_BIAS><<<dim3(8, 64, 1), dim3(256), 0, stream>>>(
      Ctx, 0LL, DD, Woutt, 0LL, DD, out, 0LL, DD, bout, nullptr, nullptr, nullptr,
      1.0f, DD);
}